// Round 9
// baseline (209.249 us; speedup 1.0000x reference)
//
#include <hip/hip_runtime.h>

// 192^3 structure tensor, fused z-streaming pipeline (4 dispatches):
//   S0: setup_coef     (extract 1D rank-1 factors from the provided 3D kernels)
//   S1: blur3d<6,1>    x -> xs     (async-staged slices; sliding xconv from stride-41 LDS)
//   S2: gradprod3d<12> xs -> P[6]  (async-staged; shared window Sx&Dx; z rings; products)
//   S3: blur3d<24,6>   P -> out    (grouped smoothing, 6 channels)
// LDS op classes (empirical r3-r8): scalar b32 any map = free; b128 on stride-32 rows = free;
// b128 at stride!=0 mod 32 = conflicted; stride-41 sliding scalar reads ~= free (2.4e6 resid).
// r7 lesson: per-thread windowed global loads = latency-bound. r8 lesson: serial
// load->waitcnt->ds_write->barrier exposes HBM latency per slice -> T14 split (issue early,
// write late): prefetch slice s+1 into regs during slice s compute.

constexpr int D  = 192;
constexpr int DD = D * D;                  // 36864
constexpr long long V = (long long)D * DD; // 7077888

// coef layout (floats):
//  [0..6] ga  [7..13] gb  [14..20] gc   (gauss z,y,x)
//  [21..29] az (9)  [30..34] bz (5)  [35..39] cz (5)
//  [40..44] ay (5)  [45..53] by (9)  [54..58] cy (5, dup)
//  [59..63] ax (5)  [64..68] bx (5)  [69..77] cx (9)
__global__ void setup_coef(const float* __restrict__ g3, const float* __restrict__ kz,
                           const float* __restrict__ ky, const float* __restrict__ kx,
                           float* __restrict__ c) {
    if (blockIdx.x != 0 || threadIdx.x != 0) return;
    float Tg = g3[0];
    for (int i = 0; i < 7; ++i) c[0 + i]  = g3[i * 49];
    for (int j = 0; j < 7; ++j) c[7 + j]  = g3[j * 7] / Tg;
    for (int k = 0; k < 7; ++k) c[14 + k] = g3[k] / Tg;
    float Tz = kz[0];                      // kz: [9,5,5]
    for (int i = 0; i < 9; ++i) c[21 + i] = kz[i * 25];
    for (int j = 0; j < 5; ++j) c[30 + j] = kz[j * 5] / Tz;
    for (int k = 0; k < 5; ++k) c[35 + k] = kz[k] / Tz;
    float Ty = ky[0];                      // ky: [5,9,5]
    for (int i = 0; i < 5; ++i) c[40 + i] = ky[i * 45];
    for (int j = 0; j < 9; ++j) c[45 + j] = ky[j * 5] / Ty;
    for (int k = 0; k < 5; ++k) c[54 + k] = ky[k] / Ty;
    float Tx = kx[0];                      // kx: [5,5,9]
    for (int i = 0; i < 5; ++i) c[59 + i] = kx[i * 45];
    for (int j = 0; j < 5; ++j) c[64 + j] = kx[j * 9] / Tx;
    for (int k = 0; k < 9; ++k) c[69 + k] = kx[k] / Tx;
}

// Bounds-checked float4 load from one z-slice (row gy, cols gx..gx+3), zero-padded.
__device__ inline float4 ldg4(const float* __restrict__ slice, int gy, int gx) {
    float4 v = {0.f, 0.f, 0.f, 0.f};
    if ((unsigned)gy < (unsigned)D) {
        const float* row = slice + gy * D;
        if ((unsigned)gx <= (unsigned)(D - 4)) {
            v = *(const float4*)(row + gx);
        } else {
            float* pv = (float*)&v;
#pragma unroll
            for (int j = 0; j < 4; ++j) {
                const int g = gx + j;
                if ((unsigned)g < (unsigned)D) pv[j] = row[g];
            }
        }
    }
    return v;
}

// Staging task li -> (row li/10, quad li%10) of a (rows x 40) region, stride-41 LDS.
__device__ inline float4 ld_task10(const float* __restrict__ slice, int y0, int x0, int li) {
    const int r = li / 10, q = li % 10;
    return ldg4(slice, y0 + r, x0 + q * 4);
}
__device__ inline void st_task41(float* __restrict__ dst, int li, float4 v) {
    const int r = li / 10, q = li % 10;
    float* d = &dst[r * 41 + q * 4];
    d[0] = v.x; d[1] = v.y; d[2] = v.z; d[3] = v.w;   // b32 class: conflict-free
}

// ---- fused separable 3D blur, z-streaming, 32x32 tile, register z-ring ----
// 1D grid, XCD-swizzled; work = tile + 36*(ch + NCH*seg)
template <int SEG, int NCH>
__global__ __launch_bounds__(256) void blur3d(const float* __restrict__ in,
                                              float* __restrict__ out,
                                              const float* __restrict__ coef) {
    __shared__ float raw[38 * 41];
    __shared__ float xt[38][32];
    const int cpx = gridDim.x >> 3;
    int w = (blockIdx.x & 7) * cpx + (blockIdx.x >> 3);
    const int tile = w % 36; w /= 36;
    const int ch = w % NCH;
    const int seg = w / NCH;
    const int tx0 = (tile % 6) * 32, ty0 = (tile / 6) * 32;
    const int z0 = seg * SEG;
    const float* src = in + (long long)ch * V;
    float* dst = out + (long long)ch * V;
    float ga[7], gb[7], gc[7];
#pragma unroll
    for (int k = 0; k < 7; ++k) { ga[k] = coef[k]; gb[k] = coef[7 + k]; gc[k] = coef[14 + k]; }
    const int tid = threadIdx.x;
    const int rr = tid >> 3;                  // 0..31
    const int cc = (tid & 7) * 4;             // 0,4,..,28
    const bool t2 = tid < 38 * 10 - 256;      // 124: second staging task
    float4 ring[7];
#pragma unroll
    for (int k = 0; k < 7; ++k) ring[k] = make_float4(0.f, 0.f, 0.f, 0.f);

    // prologue: prefetch first slice into registers
    float4 p0 = make_float4(0.f, 0.f, 0.f, 0.f), p1 = p0;
    if (z0 - 3 >= 0) {
        const float* sl = src + (long long)(z0 - 3) * DD;
        p0 = ld_task10(sl, ty0 - 3, tx0 - 4, tid);
        if (t2) p1 = ld_task10(sl, ty0 - 3, tx0 - 4, tid + 256);
    }

    for (int s = z0 - 3; s < z0 + SEG + 3; ++s) {
        const bool inz = (s >= 0 && s < D);
        if (inz) {                              // write-late: staged regs -> LDS
            st_task41(raw, tid, p0);
            if (t2) st_task41(raw, tid + 256, p1);
        }
        __syncthreads();                        // raw ready; prior xt readers done
        const int sn = s + 1;                   // issue-early: prefetch next slice
        if (sn < z0 + SEG + 3 && sn >= 0 && sn < D) {
            const float* sl = src + (long long)sn * DD;
            p0 = ld_task10(sl, ty0 - 3, tx0 - 4, tid);
            if (t2) p1 = ld_task10(sl, ty0 - 3, tx0 - 4, tid + 256);
        }
        if (inz) {
            // 4-output sliding-window xconv: 10 scalar reads -> 4 outputs, b128 xt write
            for (int li = tid; li < 38 * 8; li += 256) {
                const int r = li >> 3, g = li & 7;
                const float* rp = &raw[r * 41 + 4 * g + 1];
                float win[10];
#pragma unroll
                for (int i = 0; i < 10; ++i) win[i] = rp[i];
                float4 o = make_float4(0.f, 0.f, 0.f, 0.f);
#pragma unroll
                for (int k = 0; k < 7; ++k) {
                    o.x += gc[k] * win[k];
                    o.y += gc[k] * win[k + 1];
                    o.z += gc[k] * win[k + 2];
                    o.w += gc[k] * win[k + 3];
                }
                *(float4*)&xt[r][4 * g] = o;
            }
        }
        __syncthreads();                        // xt ready; raw readers done
        float4 yv = make_float4(0.f, 0.f, 0.f, 0.f);
        if (inz) {
#pragma unroll
            for (int k = 0; k < 7; ++k) {
                const float4 v = *(const float4*)&xt[rr + k][cc];
                yv.x += gb[k] * v.x; yv.y += gb[k] * v.y;
                yv.z += gb[k] * v.z; yv.w += gb[k] * v.w;
            }
        }
#pragma unroll
        for (int k = 0; k < 6; ++k) ring[k] = ring[k + 1];
        ring[6] = yv;
        const int z = s - 3;
        if (z >= z0) {
            float4 a = make_float4(0.f, 0.f, 0.f, 0.f);
#pragma unroll
            for (int k = 0; k < 7; ++k) {
                a.x += ga[k] * ring[k].x; a.y += ga[k] * ring[k].y;
                a.z += ga[k] * ring[k].z; a.w += ga[k] * ring[k].w;
            }
            *(float4*)(dst + (long long)z * DD + (ty0 + rr) * D + tx0 + cc) = a;
        }
    }
}

// ---- fused gradients + products, z-streaming, 32x16 tile, register rings ----
// 1D grid, XCD-swizzled; work = tile + 72*seg
template <int SEG>
__global__ __launch_bounds__(256) void gradprod3d(const float* __restrict__ xs,
                                                  float* __restrict__ P,
                                                  const float* __restrict__ coef) {
    __shared__ float raw[24 * 41];
    __shared__ float X1[24][32];
    __shared__ float X2[24][32];
    const int cpx = gridDim.x >> 3;
    int w = (blockIdx.x & 7) * cpx + (blockIdx.x >> 3);
    const int tile = w % 72;
    const int seg = w / 72;
    const int tx0 = (tile % 6) * 32, ty0 = (tile / 6) * 16;
    const int z0 = seg * SEG;
    float az[9], ay[5], ax[5], bz[5], by[9], bx[5], czc[5], cxc[9];
#pragma unroll
    for (int k = 0; k < 9; ++k) az[k] = coef[21 + k];
#pragma unroll
    for (int k = 0; k < 5; ++k) ay[k] = coef[40 + k];
#pragma unroll
    for (int k = 0; k < 5; ++k) ax[k] = coef[59 + k];
#pragma unroll
    for (int k = 0; k < 5; ++k) bz[k] = coef[30 + k];
#pragma unroll
    for (int k = 0; k < 9; ++k) by[k] = coef[45 + k];
#pragma unroll
    for (int k = 0; k < 5; ++k) bx[k] = coef[64 + k];
#pragma unroll
    for (int k = 0; k < 5; ++k) czc[k] = coef[35 + k];
#pragma unroll
    for (int k = 0; k < 9; ++k) cxc[k] = coef[69 + k];
    const int tid = threadIdx.x;
    const int rr = tid >> 4;                   // 0..15
    const int cc = (tid & 15) * 2;             // 0,2,..,30
    const bool hast = tid < 240;               // 24*10 staging tasks
    float2 R1[9], R2[7], R3[7];
#pragma unroll
    for (int k = 0; k < 9; ++k) R1[k] = make_float2(0.f, 0.f);
#pragma unroll
    for (int k = 0; k < 7; ++k) { R2[k] = make_float2(0.f, 0.f); R3[k] = make_float2(0.f, 0.f); }

    // prologue prefetch
    float4 p0 = make_float4(0.f, 0.f, 0.f, 0.f);
    if (z0 - 4 >= 0 && hast)
        p0 = ld_task10(xs + (long long)(z0 - 4) * DD, ty0 - 4, tx0 - 4, tid);

    for (int s = z0 - 4; s < z0 + SEG + 4; ++s) {
        const bool inz = (s >= 0 && s < D);
        if (inz && hast) st_task41(raw, tid, p0);
        __syncthreads();                        // raw ready; prior X readers done
        const int sn = s + 1;
        if (sn < z0 + SEG + 4 && sn >= 0 && sn < D && hast)
            p0 = ld_task10(xs + (long long)sn * DD, ty0 - 4, tx0 - 4, tid);
        if (inz && tid < 192) {
            // 12-read window serves the 5-tap (X1) and 9-tap (X2) x-convs, 4 outputs each
            const int r = tid >> 3, g = tid & 7;
            const float* rp = &raw[r * 41 + 4 * g];
            float win[12];
#pragma unroll
            for (int i = 0; i < 12; ++i) win[i] = rp[i];
            float4 o1 = make_float4(0.f, 0.f, 0.f, 0.f);
            float4 o2 = make_float4(0.f, 0.f, 0.f, 0.f);
#pragma unroll
            for (int k = 0; k < 5; ++k) {
                o1.x += czc[k] * win[2 + k];
                o1.y += czc[k] * win[3 + k];
                o1.z += czc[k] * win[4 + k];
                o1.w += czc[k] * win[5 + k];
            }
#pragma unroll
            for (int k = 0; k < 9; ++k) {
                o2.x += cxc[k] * win[k];
                o2.y += cxc[k] * win[1 + k];
                o2.z += cxc[k] * win[2 + k];
                o2.w += cxc[k] * win[3 + k];
            }
            *(float4*)&X1[r][4 * g] = o1;
            *(float4*)&X2[r][4 * g] = o2;
        }
        __syncthreads();                        // X1/X2 ready; raw readers done
        float2 t1 = make_float2(0.f, 0.f), t2 = t1, t3 = t1;
        if (inz) {
#pragma unroll
            for (int k = 0; k < 5; ++k) {
                const float2 v = *(const float2*)&X1[rr + 2 + k][cc];
                t1.x += bz[k] * v.x; t1.y += bz[k] * v.y;
            }
#pragma unroll
            for (int k = 0; k < 9; ++k) {
                const float2 v = *(const float2*)&X1[rr + k][cc];
                t2.x += by[k] * v.x; t2.y += by[k] * v.y;
            }
#pragma unroll
            for (int k = 0; k < 5; ++k) {
                const float2 v = *(const float2*)&X2[rr + 2 + k][cc];
                t3.x += bx[k] * v.x; t3.y += bx[k] * v.y;
            }
        }
#pragma unroll
        for (int k = 0; k < 8; ++k) R1[k] = R1[k + 1];
        R1[8] = t1;
#pragma unroll
        for (int k = 0; k < 6; ++k) { R2[k] = R2[k + 1]; R3[k] = R3[k + 1]; }
        R2[6] = t2; R3[6] = t3;
        const int z = s - 4;
        if (z >= z0) {
            float gz0 = 0.f, gz1 = 0.f, gy0 = 0.f, gy1 = 0.f, gx0 = 0.f, gx1 = 0.f;
#pragma unroll
            for (int k = 0; k < 9; ++k) { gz0 += az[k] * R1[k].x; gz1 += az[k] * R1[k].y; }
#pragma unroll
            for (int k = 0; k < 5; ++k) {
                gy0 += ay[k] * R2[k].x; gy1 += ay[k] * R2[k].y;
                gx0 += ax[k] * R3[k].x; gx1 += ax[k] * R3[k].y;
            }
            float* o = P + (long long)z * DD + (ty0 + rr) * D + tx0 + cc;
            float2 wv;
            wv.x = gz0 * gz0; wv.y = gz1 * gz1; *(float2*)(o + 0 * V) = wv;
            wv.x = gy0 * gz0; wv.y = gy1 * gz1; *(float2*)(o + 1 * V) = wv;
            wv.x = gx0 * gz0; wv.y = gx1 * gz1; *(float2*)(o + 2 * V) = wv;
            wv.x = gy0 * gy0; wv.y = gy1 * gy1; *(float2*)(o + 3 * V) = wv;
            wv.x = gx0 * gy0; wv.y = gx1 * gy1; *(float2*)(o + 4 * V) = wv;
            wv.x = gx0 * gx0; wv.y = gx1 * gx1; *(float2*)(o + 5 * V) = wv;
        }
    }
}

extern "C" void kernel_launch(void* const* d_in, const int* in_sizes, int n_in,
                              void* d_out, int out_size, void* d_ws, size_t ws_size,
                              hipStream_t stream) {
    const float* x  = (const float*)d_in[0];
    const float* g3 = (const float*)d_in[1];
    const float* kz = (const float*)d_in[2];
    const float* ky = (const float*)d_in[3];
    const float* kx = (const float*)d_in[4];
    float* out = (float*)d_out;

    float* coef = (float*)d_ws;
    float* P  = coef + 128;          // 6*V floats
    float* xs = P + 6 * V;           // V floats

    setup_coef<<<1, 64, 0, stream>>>(g3, kz, ky, kx, coef);

    // S1: Gaussian pre-smooth  x -> xs   (36 tiles x 32 segs = 1152 blocks)
    blur3d<6, 1><<<1152, 256, 0, stream>>>(x, xs, coef);

    // S2: gradients + products  xs -> P  (72 tiles x 16 segs = 1152 blocks)
    gradprod3d<12><<<1152, 256, 0, stream>>>(xs, P, coef);

    // S3: grouped smoothing  P -> out    (36 tiles x 6 ch x 8 segs = 1728 blocks)
    blur3d<24, 6><<<1728, 256, 0, stream>>>(P, out, coef);
}

// Round 10
// 208.210 us; speedup vs baseline: 1.0050x; 1.0050x over previous
//
#include <hip/hip_runtime.h>

// 192^3 structure tensor, fused z-streaming pipeline (4 dispatches):
//   S0: setup_coef     (extract 1D rank-1 factors from the provided 3D kernels)
//   S1: blur3d<6,1>    x -> xs     (r8-proven: coop stage; sliding xconv from stride-41 LDS)
//   S2: gradprod3d<12> xs -> P[6]  (r8-proven: shared window Sx&Dx; z rings; products)
//   S3: blur3d2<24,6>  P -> out    (2 slices/iter: 1 barrier per slice, 4-deep load issue)
// LDS op classes (empirical r3-r8): scalar b32 any map = free; b128 on stride-32 rows = free;
// b128 at stride!=0 mod 32 = conflicted; stride-41 sliding scalar reads ~= free.
// r7 lesson: per-thread windowed global loads = latency-bound. r9 lesson: register-prefetch
// across barriers regresses (live-range + occupancy). This round: halve barrier count.

constexpr int D  = 192;
constexpr int DD = D * D;                  // 36864
constexpr long long V = (long long)D * DD; // 7077888

// coef layout (floats):
//  [0..6] ga  [7..13] gb  [14..20] gc   (gauss z,y,x)
//  [21..29] az (9)  [30..34] bz (5)  [35..39] cz (5)
//  [40..44] ay (5)  [45..53] by (9)  [54..58] cy (5, dup)
//  [59..63] ax (5)  [64..68] bx (5)  [69..77] cx (9)
__global__ void setup_coef(const float* __restrict__ g3, const float* __restrict__ kz,
                           const float* __restrict__ ky, const float* __restrict__ kx,
                           float* __restrict__ c) {
    if (blockIdx.x != 0 || threadIdx.x != 0) return;
    float Tg = g3[0];
    for (int i = 0; i < 7; ++i) c[0 + i]  = g3[i * 49];
    for (int j = 0; j < 7; ++j) c[7 + j]  = g3[j * 7] / Tg;
    for (int k = 0; k < 7; ++k) c[14 + k] = g3[k] / Tg;
    float Tz = kz[0];                      // kz: [9,5,5]
    for (int i = 0; i < 9; ++i) c[21 + i] = kz[i * 25];
    for (int j = 0; j < 5; ++j) c[30 + j] = kz[j * 5] / Tz;
    for (int k = 0; k < 5; ++k) c[35 + k] = kz[k] / Tz;
    float Ty = ky[0];                      // ky: [5,9,5]
    for (int i = 0; i < 5; ++i) c[40 + i] = ky[i * 45];
    for (int j = 0; j < 9; ++j) c[45 + j] = ky[j * 5] / Ty;
    for (int k = 0; k < 5; ++k) c[54 + k] = ky[k] / Ty;
    float Tx = kx[0];                      // kx: [5,5,9]
    for (int i = 0; i < 5; ++i) c[59 + i] = kx[i * 45];
    for (int j = 0; j < 5; ++j) c[64 + j] = kx[j * 9] / Tx;
    for (int k = 0; k < 9; ++k) c[69 + k] = kx[k] / Tx;
}

// Bounds-checked float4 load from one z-slice (row gy, cols gx..gx+3), zero-padded.
__device__ inline float4 ldg4(const float* __restrict__ slice, int gy, int gx) {
    float4 v = {0.f, 0.f, 0.f, 0.f};
    if ((unsigned)gy < (unsigned)D) {
        const float* row = slice + gy * D;
        if ((unsigned)gx <= (unsigned)(D - 4)) {
            v = *(const float4*)(row + gx);
        } else {
            float* pv = (float*)&v;
#pragma unroll
            for (int j = 0; j < 4; ++j) {
                const int g = gx + j;
                if ((unsigned)g < (unsigned)D) pv[j] = row[g];
            }
        }
    }
    return v;
}

// Staging task li -> (row li/10, quad li%10) of a (rows x 40) region, stride-41 LDS.
__device__ inline float4 ld_task10(const float* __restrict__ slice, int y0, int x0, int li) {
    const int r = li / 10, q = li % 10;
    return ldg4(slice, y0 + r, x0 + q * 4);
}
__device__ inline void st_task41(float* __restrict__ dst, int li, float4 v) {
    const int r = li / 10, q = li % 10;
    float* d = &dst[r * 41 + q * 4];
    d[0] = v.x; d[1] = v.y; d[2] = v.z; d[3] = v.w;   // b32 class: conflict-free
}

// Cooperative stage of one (rows x 40) slice region into stride-41 LDS (r8-proven).
__device__ inline void load_slice41(const float* __restrict__ src, float* __restrict__ dst,
                                    int rows, int y0, int x0) {
    const int nq = rows * 10;
    for (int li = threadIdx.x; li < nq; li += 256) {
        st_task41(dst, li, ld_task10(src, y0, x0, li));
    }
}

// ---- S1 kernel: fused separable 3D blur, 1 slice/iter (r8-proven) ----
template <int SEG, int NCH>
__global__ __launch_bounds__(256) void blur3d(const float* __restrict__ in,
                                              float* __restrict__ out,
                                              const float* __restrict__ coef) {
    __shared__ float raw[38 * 41];
    __shared__ float xt[38][32];
    const int cpx = gridDim.x >> 3;
    int w = (blockIdx.x & 7) * cpx + (blockIdx.x >> 3);
    const int tile = w % 36; w /= 36;
    const int ch = w % NCH;
    const int seg = w / NCH;
    const int tx0 = (tile % 6) * 32, ty0 = (tile / 6) * 32;
    const int z0 = seg * SEG;
    const float* src = in + (long long)ch * V;
    float* dst = out + (long long)ch * V;
    float ga[7], gb[7], gc[7];
#pragma unroll
    for (int k = 0; k < 7; ++k) { ga[k] = coef[k]; gb[k] = coef[7 + k]; gc[k] = coef[14 + k]; }
    const int rr = threadIdx.x >> 3;          // 0..31
    const int cc = (threadIdx.x & 7) * 4;     // 0,4,..,28
    float4 ring[7];
#pragma unroll
    for (int k = 0; k < 7; ++k) ring[k] = make_float4(0.f, 0.f, 0.f, 0.f);

    for (int s = z0 - 3; s < z0 + SEG + 3; ++s) {
        const bool inz = (s >= 0 && s < D);
        if (inz) load_slice41(src + (long long)s * DD, raw, 38, ty0 - 3, tx0 - 4);
        __syncthreads();
        if (inz) {
            for (int li = threadIdx.x; li < 38 * 8; li += 256) {
                const int r = li >> 3, g = li & 7;
                const float* rp = &raw[r * 41 + 4 * g + 1];
                float win[10];
#pragma unroll
                for (int i = 0; i < 10; ++i) win[i] = rp[i];
                float4 o = make_float4(0.f, 0.f, 0.f, 0.f);
#pragma unroll
                for (int k = 0; k < 7; ++k) {
                    o.x += gc[k] * win[k];
                    o.y += gc[k] * win[k + 1];
                    o.z += gc[k] * win[k + 2];
                    o.w += gc[k] * win[k + 3];
                }
                *(float4*)&xt[r][4 * g] = o;
            }
        }
        __syncthreads();
        float4 yv = make_float4(0.f, 0.f, 0.f, 0.f);
        if (inz) {
#pragma unroll
            for (int k = 0; k < 7; ++k) {
                const float4 v = *(const float4*)&xt[rr + k][cc];
                yv.x += gb[k] * v.x; yv.y += gb[k] * v.y;
                yv.z += gb[k] * v.z; yv.w += gb[k] * v.w;
            }
        }
#pragma unroll
        for (int k = 0; k < 6; ++k) ring[k] = ring[k + 1];
        ring[6] = yv;
        const int z = s - 3;
        if (z >= z0) {
            float4 a = make_float4(0.f, 0.f, 0.f, 0.f);
#pragma unroll
            for (int k = 0; k < 7; ++k) {
                a.x += ga[k] * ring[k].x; a.y += ga[k] * ring[k].y;
                a.z += ga[k] * ring[k].z; a.w += ga[k] * ring[k].w;
            }
            *(float4*)(dst + (long long)z * DD + (ty0 + rr) * D + tx0 + cc) = a;
        }
    }
}

// ---- S3 kernel: fused separable 3D blur, 2 slices/iter (1 barrier per slice) ----
template <int SEG, int NCH>
__global__ __launch_bounds__(256) void blur3d2(const float* __restrict__ in,
                                               float* __restrict__ out,
                                               const float* __restrict__ coef) {
    __shared__ float raw[2][38 * 41];
    __shared__ float xt[2][38][32];
    const int cpx = gridDim.x >> 3;
    int w = (blockIdx.x & 7) * cpx + (blockIdx.x >> 3);
    const int tile = w % 36; w /= 36;
    const int ch = w % NCH;
    const int seg = w / NCH;
    const int tx0 = (tile % 6) * 32, ty0 = (tile / 6) * 32;
    const int z0 = seg * SEG;
    const float* src = in + (long long)ch * V;
    float* dst = out + (long long)ch * V;
    float ga[7], gb[7], gc[7];
#pragma unroll
    for (int k = 0; k < 7; ++k) { ga[k] = coef[k]; gb[k] = coef[7 + k]; gc[k] = coef[14 + k]; }
    const int tid = threadIdx.x;
    const int rr = tid >> 3;                  // 0..31
    const int cc = (tid & 7) * 4;             // 0,4,..,28
    const bool t2 = tid < 38 * 10 - 256;      // 124: second staging task
    float4 ring[7];
#pragma unroll
    for (int k = 0; k < 7; ++k) ring[k] = make_float4(0.f, 0.f, 0.f, 0.f);

    // window [z0-3, z0+SEG+2] has SEG+6 slices (even for even SEG) -> exact pairs
    for (int s = z0 - 3; s < z0 + SEG + 3; s += 2) {
        const bool inz0 = (s >= 0 && s < D);
        const bool inz1 = (s + 1 >= 0 && s + 1 < D);
        // issue all 4 staged loads first (MLP), then LDS writes
        float4 a0 = make_float4(0.f, 0.f, 0.f, 0.f), a1 = a0, b0 = a0, b1 = a0;
        if (inz0) {
            const float* sl = src + (long long)s * DD;
            a0 = ld_task10(sl, ty0 - 3, tx0 - 4, tid);
            if (t2) a1 = ld_task10(sl, ty0 - 3, tx0 - 4, tid + 256);
        }
        if (inz1) {
            const float* sl = src + (long long)(s + 1) * DD;
            b0 = ld_task10(sl, ty0 - 3, tx0 - 4, tid);
            if (t2) b1 = ld_task10(sl, ty0 - 3, tx0 - 4, tid + 256);
        }
        if (inz0) { st_task41(raw[0], tid, a0); if (t2) st_task41(raw[0], tid + 256, a1); }
        if (inz1) { st_task41(raw[1], tid, b0); if (t2) st_task41(raw[1], tid + 256, b1); }
        __syncthreads();                        // raw[0/1] ready; prior xt readers done
        for (int li = tid; li < 2 * 304; li += 256) {
            const int sl = (li >= 304) ? 1 : 0;
            const int t = li - sl * 304;
            if (sl ? inz1 : inz0) {
                const int r = t >> 3, g = t & 7;
                const float* rp = &raw[sl][r * 41 + 4 * g + 1];
                float win[10];
#pragma unroll
                for (int i = 0; i < 10; ++i) win[i] = rp[i];
                float4 o = make_float4(0.f, 0.f, 0.f, 0.f);
#pragma unroll
                for (int k = 0; k < 7; ++k) {
                    o.x += gc[k] * win[k];
                    o.y += gc[k] * win[k + 1];
                    o.z += gc[k] * win[k + 2];
                    o.w += gc[k] * win[k + 3];
                }
                *(float4*)&xt[sl][r][4 * g] = o;
            }
        }
        __syncthreads();                        // xt ready; raw readers done
        // slice s
        {
            float4 yv = make_float4(0.f, 0.f, 0.f, 0.f);
            if (inz0) {
#pragma unroll
                for (int k = 0; k < 7; ++k) {
                    const float4 v = *(const float4*)&xt[0][rr + k][cc];
                    yv.x += gb[k] * v.x; yv.y += gb[k] * v.y;
                    yv.z += gb[k] * v.z; yv.w += gb[k] * v.w;
                }
            }
#pragma unroll
            for (int k = 0; k < 6; ++k) ring[k] = ring[k + 1];
            ring[6] = yv;
            const int z = s - 3;
            if (z >= z0) {
                float4 a = make_float4(0.f, 0.f, 0.f, 0.f);
#pragma unroll
                for (int k = 0; k < 7; ++k) {
                    a.x += ga[k] * ring[k].x; a.y += ga[k] * ring[k].y;
                    a.z += ga[k] * ring[k].z; a.w += ga[k] * ring[k].w;
                }
                *(float4*)(dst + (long long)z * DD + (ty0 + rr) * D + tx0 + cc) = a;
            }
        }
        // slice s+1
        {
            float4 yv = make_float4(0.f, 0.f, 0.f, 0.f);
            if (inz1) {
#pragma unroll
                for (int k = 0; k < 7; ++k) {
                    const float4 v = *(const float4*)&xt[1][rr + k][cc];
                    yv.x += gb[k] * v.x; yv.y += gb[k] * v.y;
                    yv.z += gb[k] * v.z; yv.w += gb[k] * v.w;
                }
            }
#pragma unroll
            for (int k = 0; k < 6; ++k) ring[k] = ring[k + 1];
            ring[6] = yv;
            const int z = s - 2;
            if (z >= z0 && z < z0 + SEG) {
                float4 a = make_float4(0.f, 0.f, 0.f, 0.f);
#pragma unroll
                for (int k = 0; k < 7; ++k) {
                    a.x += ga[k] * ring[k].x; a.y += ga[k] * ring[k].y;
                    a.z += ga[k] * ring[k].z; a.w += ga[k] * ring[k].w;
                }
                *(float4*)(dst + (long long)z * DD + (ty0 + rr) * D + tx0 + cc) = a;
            }
        }
    }
}

// ---- S2 kernel: fused gradients + products, z-streaming (r8-proven) ----
template <int SEG>
__global__ __launch_bounds__(256) void gradprod3d(const float* __restrict__ xs,
                                                  float* __restrict__ P,
                                                  const float* __restrict__ coef) {
    __shared__ float raw[24 * 41];
    __shared__ float X1[24][32];
    __shared__ float X2[24][32];
    const int cpx = gridDim.x >> 3;
    int w = (blockIdx.x & 7) * cpx + (blockIdx.x >> 3);
    const int tile = w % 72;
    const int seg = w / 72;
    const int tx0 = (tile % 6) * 32, ty0 = (tile / 6) * 16;
    const int z0 = seg * SEG;
    float az[9], ay[5], ax[5], bz[5], by[9], bx[5], czc[5], cxc[9];
#pragma unroll
    for (int k = 0; k < 9; ++k) az[k] = coef[21 + k];
#pragma unroll
    for (int k = 0; k < 5; ++k) ay[k] = coef[40 + k];
#pragma unroll
    for (int k = 0; k < 5; ++k) ax[k] = coef[59 + k];
#pragma unroll
    for (int k = 0; k < 5; ++k) bz[k] = coef[30 + k];
#pragma unroll
    for (int k = 0; k < 9; ++k) by[k] = coef[45 + k];
#pragma unroll
    for (int k = 0; k < 5; ++k) bx[k] = coef[64 + k];
#pragma unroll
    for (int k = 0; k < 5; ++k) czc[k] = coef[35 + k];
#pragma unroll
    for (int k = 0; k < 9; ++k) cxc[k] = coef[69 + k];
    const int rr = threadIdx.x >> 4;           // 0..15
    const int cc = (threadIdx.x & 15) * 2;     // 0,2,..,30
    float2 R1[9], R2[7], R3[7];
#pragma unroll
    for (int k = 0; k < 9; ++k) R1[k] = make_float2(0.f, 0.f);
#pragma unroll
    for (int k = 0; k < 7; ++k) { R2[k] = make_float2(0.f, 0.f); R3[k] = make_float2(0.f, 0.f); }

    for (int s = z0 - 4; s < z0 + SEG + 4; ++s) {
        const bool inz = (s >= 0 && s < D);
        if (inz) load_slice41(xs + (long long)s * DD, raw, 24, ty0 - 4, tx0 - 4);
        __syncthreads();
        if (inz && threadIdx.x < 192) {
            const int r = threadIdx.x >> 3, g = threadIdx.x & 7;
            const float* rp = &raw[r * 41 + 4 * g];
            float win[12];
#pragma unroll
            for (int i = 0; i < 12; ++i) win[i] = rp[i];
            float4 o1 = make_float4(0.f, 0.f, 0.f, 0.f);
            float4 o2 = make_float4(0.f, 0.f, 0.f, 0.f);
#pragma unroll
            for (int k = 0; k < 5; ++k) {
                o1.x += czc[k] * win[2 + k];
                o1.y += czc[k] * win[3 + k];
                o1.z += czc[k] * win[4 + k];
                o1.w += czc[k] * win[5 + k];
            }
#pragma unroll
            for (int k = 0; k < 9; ++k) {
                o2.x += cxc[k] * win[k];
                o2.y += cxc[k] * win[1 + k];
                o2.z += cxc[k] * win[2 + k];
                o2.w += cxc[k] * win[3 + k];
            }
            *(float4*)&X1[r][4 * g] = o1;
            *(float4*)&X2[r][4 * g] = o2;
        }
        __syncthreads();
        float2 t1 = make_float2(0.f, 0.f), t2 = t1, t3 = t1;
        if (inz) {
#pragma unroll
            for (int k = 0; k < 5; ++k) {
                const float2 v = *(const float2*)&X1[rr + 2 + k][cc];
                t1.x += bz[k] * v.x; t1.y += bz[k] * v.y;
            }
#pragma unroll
            for (int k = 0; k < 9; ++k) {
                const float2 v = *(const float2*)&X1[rr + k][cc];
                t2.x += by[k] * v.x; t2.y += by[k] * v.y;
            }
#pragma unroll
            for (int k = 0; k < 5; ++k) {
                const float2 v = *(const float2*)&X2[rr + 2 + k][cc];
                t3.x += bx[k] * v.x; t3.y += bx[k] * v.y;
            }
        }
#pragma unroll
        for (int k = 0; k < 8; ++k) R1[k] = R1[k + 1];
        R1[8] = t1;
#pragma unroll
        for (int k = 0; k < 6; ++k) { R2[k] = R2[k + 1]; R3[k] = R3[k + 1]; }
        R2[6] = t2; R3[6] = t3;
        const int z = s - 4;
        if (z >= z0) {
            float gz0 = 0.f, gz1 = 0.f, gy0 = 0.f, gy1 = 0.f, gx0 = 0.f, gx1 = 0.f;
#pragma unroll
            for (int k = 0; k < 9; ++k) { gz0 += az[k] * R1[k].x; gz1 += az[k] * R1[k].y; }
#pragma unroll
            for (int k = 0; k < 5; ++k) {
                gy0 += ay[k] * R2[k].x; gy1 += ay[k] * R2[k].y;
                gx0 += ax[k] * R3[k].x; gx1 += ax[k] * R3[k].y;
            }
            float* o = P + (long long)z * DD + (ty0 + rr) * D + tx0 + cc;
            float2 wv;
            wv.x = gz0 * gz0; wv.y = gz1 * gz1; *(float2*)(o + 0 * V) = wv;
            wv.x = gy0 * gz0; wv.y = gy1 * gz1; *(float2*)(o + 1 * V) = wv;
            wv.x = gx0 * gz0; wv.y = gx1 * gz1; *(float2*)(o + 2 * V) = wv;
            wv.x = gy0 * gy0; wv.y = gy1 * gy1; *(float2*)(o + 3 * V) = wv;
            wv.x = gx0 * gy0; wv.y = gx1 * gy1; *(float2*)(o + 4 * V) = wv;
            wv.x = gx0 * gx0; wv.y = gx1 * gx1; *(float2*)(o + 5 * V) = wv;
        }
    }
}

extern "C" void kernel_launch(void* const* d_in, const int* in_sizes, int n_in,
                              void* d_out, int out_size, void* d_ws, size_t ws_size,
                              hipStream_t stream) {
    const float* x  = (const float*)d_in[0];
    const float* g3 = (const float*)d_in[1];
    const float* kz = (const float*)d_in[2];
    const float* ky = (const float*)d_in[3];
    const float* kx = (const float*)d_in[4];
    float* out = (float*)d_out;

    float* coef = (float*)d_ws;
    float* P  = coef + 128;          // 6*V floats
    float* xs = P + 6 * V;           // V floats

    setup_coef<<<1, 64, 0, stream>>>(g3, kz, ky, kx, coef);

    // S1: Gaussian pre-smooth  x -> xs   (36 tiles x 32 segs = 1152 blocks)
    blur3d<6, 1><<<1152, 256, 0, stream>>>(x, xs, coef);

    // S2: gradients + products  xs -> P  (72 tiles x 16 segs = 1152 blocks)
    gradprod3d<12><<<1152, 256, 0, stream>>>(xs, P, coef);

    // S3: grouped smoothing  P -> out    (36 tiles x 6 ch x 8 segs = 1728 blocks)
    blur3d2<24, 6><<<1728, 256, 0, stream>>>(P, out, coef);
}

// Round 11
// 168.645 us; speedup vs baseline: 1.2408x; 1.2346x over previous
//
#include <hip/hip_runtime.h>

// 192^3 structure tensor, fused z-streaming pipeline (4 dispatches):
//   S0: setup_coef    (extract 1D rank-1 factors from the provided 3D kernels)
//   S1: blur3d<6,1,false>  x -> xs    (r8-proven schedule)
//   S2: grad3d<12>    xs -> G[3]      (gz,gy,gx only — products deferred to S3)
//   S3: blur3d<24,6,true>  G -> out   (stage task loads G_a,G_b, multiplies in regs)
// r8-proven LDS classes only: stride-41 raw (b32 scalar ops), stride-32 xt (b128,
// 8-row x 8-quad map). r9/r10 lesson: scheduling restructures around this kernel
// (reg-prefetch, 2-slice batching) regress via VGPR/LDS growth; keep 32-VGPR schedule.
// This round: S3 reads the 85 MB gradient set (L3-resident) instead of 166 MB P.

constexpr int D  = 192;
constexpr int DD = D * D;                  // 36864
constexpr long long V = (long long)D * DD; // 7077888

// coef layout (floats):
//  [0..6] ga  [7..13] gb  [14..20] gc   (gauss z,y,x)
//  [21..29] az (9)  [30..34] bz (5)  [35..39] cz (5)
//  [40..44] ay (5)  [45..53] by (9)  [54..58] cy (5, dup)
//  [59..63] ax (5)  [64..68] bx (5)  [69..77] cx (9)
__global__ void setup_coef(const float* __restrict__ g3, const float* __restrict__ kz,
                           const float* __restrict__ ky, const float* __restrict__ kx,
                           float* __restrict__ c) {
    if (blockIdx.x != 0 || threadIdx.x != 0) return;
    float Tg = g3[0];
    for (int i = 0; i < 7; ++i) c[0 + i]  = g3[i * 49];
    for (int j = 0; j < 7; ++j) c[7 + j]  = g3[j * 7] / Tg;
    for (int k = 0; k < 7; ++k) c[14 + k] = g3[k] / Tg;
    float Tz = kz[0];                      // kz: [9,5,5]
    for (int i = 0; i < 9; ++i) c[21 + i] = kz[i * 25];
    for (int j = 0; j < 5; ++j) c[30 + j] = kz[j * 5] / Tz;
    for (int k = 0; k < 5; ++k) c[35 + k] = kz[k] / Tz;
    float Ty = ky[0];                      // ky: [5,9,5]
    for (int i = 0; i < 5; ++i) c[40 + i] = ky[i * 45];
    for (int j = 0; j < 9; ++j) c[45 + j] = ky[j * 5] / Ty;
    for (int k = 0; k < 5; ++k) c[54 + k] = ky[k] / Ty;
    float Tx = kx[0];                      // kx: [5,5,9]
    for (int i = 0; i < 5; ++i) c[59 + i] = kx[i * 45];
    for (int j = 0; j < 5; ++j) c[64 + j] = kx[j * 9] / Tx;
    for (int k = 0; k < 9; ++k) c[69 + k] = kx[k] / Tx;
}

// Bounds-checked float4 load from one z-slice (row gy, cols gx..gx+3), zero-padded.
__device__ inline float4 ldg4(const float* __restrict__ slice, int gy, int gx) {
    float4 v = {0.f, 0.f, 0.f, 0.f};
    if ((unsigned)gy < (unsigned)D) {
        const float* row = slice + gy * D;
        if ((unsigned)gx <= (unsigned)(D - 4)) {
            v = *(const float4*)(row + gx);
        } else {
            float* pv = (float*)&v;
#pragma unroll
            for (int j = 0; j < 4; ++j) {
                const int g = gx + j;
                if ((unsigned)g < (unsigned)D) pv[j] = row[g];
            }
        }
    }
    return v;
}

// Staging task li -> (row li/10, quad li%10) of a (rows x 40) region, stride-41 LDS.
__device__ inline float4 ld_task10(const float* __restrict__ slice, int y0, int x0, int li) {
    const int r = li / 10, q = li % 10;
    return ldg4(slice, y0 + r, x0 + q * 4);
}
__device__ inline void st_task41(float* __restrict__ dst, int li, float4 v) {
    const int r = li / 10, q = li % 10;
    float* d = &dst[r * 41 + q * 4];
    d[0] = v.x; d[1] = v.y; d[2] = v.z; d[3] = v.w;   // b32 class: conflict-free
}

// ---- fused separable 3D blur, z-streaming, 32x32 tile, register z-ring ----
// PROD=true: stage task loads two gradient fields and multiplies (product on the fly).
// 1D grid, XCD-swizzled; work = tile + 36*(ch + NCH*seg)
template <int SEG, int NCH, bool PROD>
__global__ __launch_bounds__(256) void blur3d(const float* __restrict__ in,
                                              float* __restrict__ out,
                                              const float* __restrict__ coef) {
    __shared__ float raw[38 * 41];
    __shared__ float xt[38][32];
    const int cpx = gridDim.x >> 3;
    int w = (blockIdx.x & 7) * cpx + (blockIdx.x >> 3);
    const int tile = w % 36; w /= 36;
    const int ch = w % NCH;
    const int seg = w / NCH;
    const int tx0 = (tile % 6) * 32, ty0 = (tile / 6) * 32;
    const int z0 = seg * SEG;
    // product channel -> gradient-field pair: [Jzz,Jzy,Jzx,Jyy,Jyx,Jxx]
    const int IA[6] = {0, 1, 2, 1, 2, 2};
    const int IB[6] = {0, 0, 0, 1, 1, 2};
    const float* srcA = in + (long long)(PROD ? IA[ch] : ch) * V;
    const float* srcB = in + (long long)(PROD ? IB[ch] : ch) * V;
    const bool same = !PROD || (IA[ch] == IB[ch]);
    float* dst = out + (long long)ch * V;
    float ga[7], gb[7], gc[7];
#pragma unroll
    for (int k = 0; k < 7; ++k) { ga[k] = coef[k]; gb[k] = coef[7 + k]; gc[k] = coef[14 + k]; }
    const int rr = threadIdx.x >> 3;          // 0..31
    const int cc = (threadIdx.x & 7) * 4;     // 0,4,..,28
    float4 ring[7];
#pragma unroll
    for (int k = 0; k < 7; ++k) ring[k] = make_float4(0.f, 0.f, 0.f, 0.f);

    for (int s = z0 - 3; s < z0 + SEG + 3; ++s) {
        const bool inz = (s >= 0 && s < D);
        if (inz) {
            const float* slA = srcA + (long long)s * DD;
            const float* slB = srcB + (long long)s * DD;
            if (same) {
                for (int li = threadIdx.x; li < 380; li += 256) {
                    float4 a = ld_task10(slA, ty0 - 3, tx0 - 4, li);
                    if (PROD) { a.x *= a.x; a.y *= a.y; a.z *= a.z; a.w *= a.w; }
                    st_task41(raw, li, a);
                }
            } else {
                for (int li = threadIdx.x; li < 380; li += 256) {
                    float4 a = ld_task10(slA, ty0 - 3, tx0 - 4, li);
                    float4 b = ld_task10(slB, ty0 - 3, tx0 - 4, li);
                    a.x *= b.x; a.y *= b.y; a.z *= b.z; a.w *= b.w;
                    st_task41(raw, li, a);
                }
            }
        }
        __syncthreads();                       // raw ready; prior xt readers done
        if (inz) {
            // 4-output sliding-window xconv: 10 scalar reads -> 4 outputs, b128 xt write
            for (int li = threadIdx.x; li < 38 * 8; li += 256) {
                const int r = li >> 3, g = li & 7;
                const float* rp = &raw[r * 41 + 4 * g + 1];
                float win[10];
#pragma unroll
                for (int i = 0; i < 10; ++i) win[i] = rp[i];
                float4 o = make_float4(0.f, 0.f, 0.f, 0.f);
#pragma unroll
                for (int k = 0; k < 7; ++k) {
                    o.x += gc[k] * win[k];
                    o.y += gc[k] * win[k + 1];
                    o.z += gc[k] * win[k + 2];
                    o.w += gc[k] * win[k + 3];
                }
                *(float4*)&xt[r][4 * g] = o;
            }
        }
        __syncthreads();                       // xt ready; raw readers done
        float4 yv = make_float4(0.f, 0.f, 0.f, 0.f);
        if (inz) {
#pragma unroll
            for (int k = 0; k < 7; ++k) {
                const float4 v = *(const float4*)&xt[rr + k][cc];
                yv.x += gb[k] * v.x; yv.y += gb[k] * v.y;
                yv.z += gb[k] * v.z; yv.w += gb[k] * v.w;
            }
        }
#pragma unroll
        for (int k = 0; k < 6; ++k) ring[k] = ring[k + 1];
        ring[6] = yv;
        const int z = s - 3;
        if (z >= z0) {
            float4 a = make_float4(0.f, 0.f, 0.f, 0.f);
#pragma unroll
            for (int k = 0; k < 7; ++k) {
                a.x += ga[k] * ring[k].x; a.y += ga[k] * ring[k].y;
                a.z += ga[k] * ring[k].z; a.w += ga[k] * ring[k].w;
            }
            *(float4*)(dst + (long long)z * DD + (ty0 + rr) * D + tx0 + cc) = a;
        }
    }
}

// ---- fused gradients, z-streaming, 32x16 tile, register rings (r8 minus products) ----
// 1D grid, XCD-swizzled; work = tile + 72*seg; writes gz,gy,gx to G[0..2]
template <int SEG>
__global__ __launch_bounds__(256) void grad3d(const float* __restrict__ xs,
                                              float* __restrict__ G,
                                              const float* __restrict__ coef) {
    __shared__ float raw[24 * 41];
    __shared__ float X1[24][32];
    __shared__ float X2[24][32];
    const int cpx = gridDim.x >> 3;
    int w = (blockIdx.x & 7) * cpx + (blockIdx.x >> 3);
    const int tile = w % 72;
    const int seg = w / 72;
    const int tx0 = (tile % 6) * 32, ty0 = (tile / 6) * 16;
    const int z0 = seg * SEG;
    float az[9], ay[5], ax[5], bz[5], by[9], bx[5], czc[5], cxc[9];
#pragma unroll
    for (int k = 0; k < 9; ++k) az[k] = coef[21 + k];
#pragma unroll
    for (int k = 0; k < 5; ++k) ay[k] = coef[40 + k];
#pragma unroll
    for (int k = 0; k < 5; ++k) ax[k] = coef[59 + k];
#pragma unroll
    for (int k = 0; k < 5; ++k) bz[k] = coef[30 + k];
#pragma unroll
    for (int k = 0; k < 9; ++k) by[k] = coef[45 + k];
#pragma unroll
    for (int k = 0; k < 5; ++k) bx[k] = coef[64 + k];
#pragma unroll
    for (int k = 0; k < 5; ++k) czc[k] = coef[35 + k];
#pragma unroll
    for (int k = 0; k < 9; ++k) cxc[k] = coef[69 + k];
    const int rr = threadIdx.x >> 4;           // 0..15
    const int cc = (threadIdx.x & 15) * 2;     // 0,2,..,30
    float2 R1[9], R2[7], R3[7];
#pragma unroll
    for (int k = 0; k < 9; ++k) R1[k] = make_float2(0.f, 0.f);
#pragma unroll
    for (int k = 0; k < 7; ++k) { R2[k] = make_float2(0.f, 0.f); R3[k] = make_float2(0.f, 0.f); }

    for (int s = z0 - 4; s < z0 + SEG + 4; ++s) {
        const bool inz = (s >= 0 && s < D);
        if (inz) {
            const float* sl = xs + (long long)s * DD;
            for (int li = threadIdx.x; li < 240; li += 256)
                st_task41(raw, li, ld_task10(sl, ty0 - 4, tx0 - 4, li));
        }
        __syncthreads();
        if (inz && threadIdx.x < 192) {
            const int r = threadIdx.x >> 3, g = threadIdx.x & 7;
            const float* rp = &raw[r * 41 + 4 * g];
            float win[12];
#pragma unroll
            for (int i = 0; i < 12; ++i) win[i] = rp[i];
            float4 o1 = make_float4(0.f, 0.f, 0.f, 0.f);
            float4 o2 = make_float4(0.f, 0.f, 0.f, 0.f);
#pragma unroll
            for (int k = 0; k < 5; ++k) {
                o1.x += czc[k] * win[2 + k];
                o1.y += czc[k] * win[3 + k];
                o1.z += czc[k] * win[4 + k];
                o1.w += czc[k] * win[5 + k];
            }
#pragma unroll
            for (int k = 0; k < 9; ++k) {
                o2.x += cxc[k] * win[k];
                o2.y += cxc[k] * win[1 + k];
                o2.z += cxc[k] * win[2 + k];
                o2.w += cxc[k] * win[3 + k];
            }
            *(float4*)&X1[r][4 * g] = o1;
            *(float4*)&X2[r][4 * g] = o2;
        }
        __syncthreads();
        float2 t1 = make_float2(0.f, 0.f), t2 = t1, t3 = t1;
        if (inz) {
#pragma unroll
            for (int k = 0; k < 5; ++k) {
                const float2 v = *(const float2*)&X1[rr + 2 + k][cc];
                t1.x += bz[k] * v.x; t1.y += bz[k] * v.y;
            }
#pragma unroll
            for (int k = 0; k < 9; ++k) {
                const float2 v = *(const float2*)&X1[rr + k][cc];
                t2.x += by[k] * v.x; t2.y += by[k] * v.y;
            }
#pragma unroll
            for (int k = 0; k < 5; ++k) {
                const float2 v = *(const float2*)&X2[rr + 2 + k][cc];
                t3.x += bx[k] * v.x; t3.y += bx[k] * v.y;
            }
        }
#pragma unroll
        for (int k = 0; k < 8; ++k) R1[k] = R1[k + 1];
        R1[8] = t1;
#pragma unroll
        for (int k = 0; k < 6; ++k) { R2[k] = R2[k + 1]; R3[k] = R3[k + 1]; }
        R2[6] = t2; R3[6] = t3;
        const int z = s - 4;
        if (z >= z0) {
            float gz0 = 0.f, gz1 = 0.f, gy0 = 0.f, gy1 = 0.f, gx0 = 0.f, gx1 = 0.f;
#pragma unroll
            for (int k = 0; k < 9; ++k) { gz0 += az[k] * R1[k].x; gz1 += az[k] * R1[k].y; }
#pragma unroll
            for (int k = 0; k < 5; ++k) {
                gy0 += ay[k] * R2[k].x; gy1 += ay[k] * R2[k].y;
                gx0 += ax[k] * R3[k].x; gx1 += ax[k] * R3[k].y;
            }
            float* o = G + (long long)z * DD + (ty0 + rr) * D + tx0 + cc;
            float2 wv;
            wv.x = gz0; wv.y = gz1; *(float2*)(o + 0 * V) = wv;
            wv.x = gy0; wv.y = gy1; *(float2*)(o + 1 * V) = wv;
            wv.x = gx0; wv.y = gx1; *(float2*)(o + 2 * V) = wv;
        }
    }
}

extern "C" void kernel_launch(void* const* d_in, const int* in_sizes, int n_in,
                              void* d_out, int out_size, void* d_ws, size_t ws_size,
                              hipStream_t stream) {
    const float* x  = (const float*)d_in[0];
    const float* g3 = (const float*)d_in[1];
    const float* kz = (const float*)d_in[2];
    const float* ky = (const float*)d_in[3];
    const float* kx = (const float*)d_in[4];
    float* out = (float*)d_out;

    float* coef = (float*)d_ws;
    float* G  = coef + 128;          // 3*V floats (gz, gy, gx)
    float* xs = G + 3 * V;           // V floats

    setup_coef<<<1, 64, 0, stream>>>(g3, kz, ky, kx, coef);

    // S1: Gaussian pre-smooth  x -> xs   (36 tiles x 32 segs = 1152 blocks)
    blur3d<6, 1, false><<<1152, 256, 0, stream>>>(x, xs, coef);

    // S2: gradients  xs -> G[3]         (72 tiles x 16 segs = 1152 blocks)
    grad3d<12><<<1152, 256, 0, stream>>>(xs, G, coef);

    // S3: products-on-the-fly + grouped smoothing  G -> out
    //     (36 tiles x 6 ch x 8 segs = 1728 blocks)
    blur3d<24, 6, true><<<1728, 256, 0, stream>>>(G, out, coef);
}

// Round 12
// 165.294 us; speedup vs baseline: 1.2659x; 1.0203x over previous
//
#include <hip/hip_runtime.h>

// 192^3 structure tensor, fused z-streaming pipeline (4 dispatches):
//   S0: setup_coef    (extract 1D rank-1 factors from the provided 3D kernels)
//   S1: blur3d<6,1,false>   x -> xs   (r8-proven schedule)
//   S2: grad3d<16>    xs -> G[3]      (gz,gy,gx only; products deferred to S3)
//   S3: blur3d<32,6,true>   G -> out  (products formed in regs at staging time)
// r8-proven LDS classes only: stride-41 raw (b32 ops), stride-32 xt (b128, 8-row x
// 8-quad, 1-row-per-thread). r9/r10: schedule restructures regress. r11: S3 is
// stall-dominated (LDS 65%, VALU 46%, HBM 28%, occ 58%) -> this round cuts work
// counts only: bigger SEG (z-halo amortization) + dual-load bounds hoist.

constexpr int D  = 192;
constexpr int DD = D * D;                  // 36864
constexpr long long V = (long long)D * DD; // 7077888

// coef layout (floats):
//  [0..6] ga  [7..13] gb  [14..20] gc   (gauss z,y,x)
//  [21..29] az (9)  [30..34] bz (5)  [35..39] cz (5)
//  [40..44] ay (5)  [45..53] by (9)  [54..58] cy (5, dup)
//  [59..63] ax (5)  [64..68] bx (5)  [69..77] cx (9)
__global__ void setup_coef(const float* __restrict__ g3, const float* __restrict__ kz,
                           const float* __restrict__ ky, const float* __restrict__ kx,
                           float* __restrict__ c) {
    if (blockIdx.x != 0 || threadIdx.x != 0) return;
    float Tg = g3[0];
    for (int i = 0; i < 7; ++i) c[0 + i]  = g3[i * 49];
    for (int j = 0; j < 7; ++j) c[7 + j]  = g3[j * 7] / Tg;
    for (int k = 0; k < 7; ++k) c[14 + k] = g3[k] / Tg;
    float Tz = kz[0];                      // kz: [9,5,5]
    for (int i = 0; i < 9; ++i) c[21 + i] = kz[i * 25];
    for (int j = 0; j < 5; ++j) c[30 + j] = kz[j * 5] / Tz;
    for (int k = 0; k < 5; ++k) c[35 + k] = kz[k] / Tz;
    float Ty = ky[0];                      // ky: [5,9,5]
    for (int i = 0; i < 5; ++i) c[40 + i] = ky[i * 45];
    for (int j = 0; j < 9; ++j) c[45 + j] = ky[j * 5] / Ty;
    for (int k = 0; k < 5; ++k) c[54 + k] = ky[k] / Ty;
    float Tx = kx[0];                      // kx: [5,5,9]
    for (int i = 0; i < 5; ++i) c[59 + i] = kx[i * 45];
    for (int j = 0; j < 5; ++j) c[64 + j] = kx[j * 9] / Tx;
    for (int k = 0; k < 9; ++k) c[69 + k] = kx[k] / Tx;
}

// Bounds-checked float4 load from one z-slice (row gy, cols gx..gx+3), zero-padded.
__device__ inline float4 ldg4(const float* __restrict__ slice, int gy, int gx) {
    float4 v = {0.f, 0.f, 0.f, 0.f};
    if ((unsigned)gy < (unsigned)D) {
        const float* row = slice + gy * D;
        if ((unsigned)gx <= (unsigned)(D - 4)) {
            v = *(const float4*)(row + gx);
        } else {
            float* pv = (float*)&v;
#pragma unroll
            for (int j = 0; j < 4; ++j) {
                const int g = gx + j;
                if ((unsigned)g < (unsigned)D) pv[j] = row[g];
            }
        }
    }
    return v;
}

// Dual-field bounds-hoisted load: computes bounds once, loads A and B rows.
__device__ inline void ldg4x2(const float* __restrict__ slA, const float* __restrict__ slB,
                              int gy, int gx, float4& a, float4& b) {
    a = make_float4(0.f, 0.f, 0.f, 0.f);
    b = a;
    if ((unsigned)gy < (unsigned)D) {
        const int ro = gy * D;
        if ((unsigned)gx <= (unsigned)(D - 4)) {
            a = *(const float4*)(slA + ro + gx);
            b = *(const float4*)(slB + ro + gx);
        } else {
            float* pa = (float*)&a;
            float* pb = (float*)&b;
#pragma unroll
            for (int j = 0; j < 4; ++j) {
                const int g = gx + j;
                if ((unsigned)g < (unsigned)D) { pa[j] = slA[ro + g]; pb[j] = slB[ro + g]; }
            }
        }
    }
}

// Staging task li -> (row li/10, quad li%10) of a (rows x 40) region, stride-41 LDS.
__device__ inline float4 ld_task10(const float* __restrict__ slice, int y0, int x0, int li) {
    const int r = li / 10, q = li % 10;
    return ldg4(slice, y0 + r, x0 + q * 4);
}
__device__ inline void st_task41(float* __restrict__ dst, int li, float4 v) {
    const int r = li / 10, q = li % 10;
    float* d = &dst[r * 41 + q * 4];
    d[0] = v.x; d[1] = v.y; d[2] = v.z; d[3] = v.w;   // b32 class: conflict-free
}

// ---- fused separable 3D blur, z-streaming, 32x32 tile, register z-ring ----
// PROD=true: stage task loads two gradient fields and multiplies (product on the fly).
// 1D grid, XCD-swizzled; work = tile + 36*(ch + NCH*seg)
template <int SEG, int NCH, bool PROD>
__global__ __launch_bounds__(256) void blur3d(const float* __restrict__ in,
                                              float* __restrict__ out,
                                              const float* __restrict__ coef) {
    __shared__ float raw[38 * 41];
    __shared__ float xt[38][32];
    const int cpx = gridDim.x >> 3;
    int w = (blockIdx.x & 7) * cpx + (blockIdx.x >> 3);
    const int tile = w % 36; w /= 36;
    const int ch = w % NCH;
    const int seg = w / NCH;
    const int tx0 = (tile % 6) * 32, ty0 = (tile / 6) * 32;
    const int z0 = seg * SEG;
    // product channel -> gradient-field pair: [Jzz,Jzy,Jzx,Jyy,Jyx,Jxx]
    const int IA[6] = {0, 1, 2, 1, 2, 2};
    const int IB[6] = {0, 0, 0, 1, 1, 2};
    const float* srcA = in + (long long)(PROD ? IA[ch] : ch) * V;
    const float* srcB = in + (long long)(PROD ? IB[ch] : ch) * V;
    const bool same = !PROD || (IA[ch] == IB[ch]);
    float* dst = out + (long long)ch * V;
    float ga[7], gb[7], gc[7];
#pragma unroll
    for (int k = 0; k < 7; ++k) { ga[k] = coef[k]; gb[k] = coef[7 + k]; gc[k] = coef[14 + k]; }
    const int rr = threadIdx.x >> 3;          // 0..31
    const int cc = (threadIdx.x & 7) * 4;     // 0,4,..,28
    float4 ring[7];
#pragma unroll
    for (int k = 0; k < 7; ++k) ring[k] = make_float4(0.f, 0.f, 0.f, 0.f);

    for (int s = z0 - 3; s < z0 + SEG + 3; ++s) {
        const bool inz = (s >= 0 && s < D);
        if (inz) {
            const float* slA = srcA + (long long)s * DD;
            const float* slB = srcB + (long long)s * DD;
            if (same) {
                for (int li = threadIdx.x; li < 380; li += 256) {
                    float4 a = ld_task10(slA, ty0 - 3, tx0 - 4, li);
                    if (PROD) { a.x *= a.x; a.y *= a.y; a.z *= a.z; a.w *= a.w; }
                    st_task41(raw, li, a);
                }
            } else {
                for (int li = threadIdx.x; li < 380; li += 256) {
                    const int r = li / 10, q = li % 10;
                    float4 a, b;
                    ldg4x2(slA, slB, ty0 - 3 + r, tx0 - 4 + q * 4, a, b);
                    a.x *= b.x; a.y *= b.y; a.z *= b.z; a.w *= b.w;
                    float* d = &raw[r * 41 + q * 4];
                    d[0] = a.x; d[1] = a.y; d[2] = a.z; d[3] = a.w;
                }
            }
        }
        __syncthreads();                       // raw ready; prior xt readers done
        if (inz) {
            // 4-output sliding-window xconv: 10 scalar reads -> 4 outputs, b128 xt write
            for (int li = threadIdx.x; li < 38 * 8; li += 256) {
                const int r = li >> 3, g = li & 7;
                const float* rp = &raw[r * 41 + 4 * g + 1];
                float win[10];
#pragma unroll
                for (int i = 0; i < 10; ++i) win[i] = rp[i];
                float4 o = make_float4(0.f, 0.f, 0.f, 0.f);
#pragma unroll
                for (int k = 0; k < 7; ++k) {
                    o.x += gc[k] * win[k];
                    o.y += gc[k] * win[k + 1];
                    o.z += gc[k] * win[k + 2];
                    o.w += gc[k] * win[k + 3];
                }
                *(float4*)&xt[r][4 * g] = o;
            }
        }
        __syncthreads();                       // xt ready; raw readers done
        float4 yv = make_float4(0.f, 0.f, 0.f, 0.f);
        if (inz) {
#pragma unroll
            for (int k = 0; k < 7; ++k) {
                const float4 v = *(const float4*)&xt[rr + k][cc];
                yv.x += gb[k] * v.x; yv.y += gb[k] * v.y;
                yv.z += gb[k] * v.z; yv.w += gb[k] * v.w;
            }
        }
#pragma unroll
        for (int k = 0; k < 6; ++k) ring[k] = ring[k + 1];
        ring[6] = yv;
        const int z = s - 3;
        if (z >= z0) {
            float4 a = make_float4(0.f, 0.f, 0.f, 0.f);
#pragma unroll
            for (int k = 0; k < 7; ++k) {
                a.x += ga[k] * ring[k].x; a.y += ga[k] * ring[k].y;
                a.z += ga[k] * ring[k].z; a.w += ga[k] * ring[k].w;
            }
            *(float4*)(dst + (long long)z * DD + (ty0 + rr) * D + tx0 + cc) = a;
        }
    }
}

// ---- fused gradients, z-streaming, 32x16 tile, register rings ----
// 1D grid, XCD-swizzled; work = tile + 72*seg; writes gz,gy,gx to G[0..2]
template <int SEG>
__global__ __launch_bounds__(256) void grad3d(const float* __restrict__ xs,
                                              float* __restrict__ G,
                                              const float* __restrict__ coef) {
    __shared__ float raw[24 * 41];
    __shared__ float X1[24][32];
    __shared__ float X2[24][32];
    const int cpx = gridDim.x >> 3;
    int w = (blockIdx.x & 7) * cpx + (blockIdx.x >> 3);
    const int tile = w % 72;
    const int seg = w / 72;
    const int tx0 = (tile % 6) * 32, ty0 = (tile / 6) * 16;
    const int z0 = seg * SEG;
    float az[9], ay[5], ax[5], bz[5], by[9], bx[5], czc[5], cxc[9];
#pragma unroll
    for (int k = 0; k < 9; ++k) az[k] = coef[21 + k];
#pragma unroll
    for (int k = 0; k < 5; ++k) ay[k] = coef[40 + k];
#pragma unroll
    for (int k = 0; k < 5; ++k) ax[k] = coef[59 + k];
#pragma unroll
    for (int k = 0; k < 5; ++k) bz[k] = coef[30 + k];
#pragma unroll
    for (int k = 0; k < 9; ++k) by[k] = coef[45 + k];
#pragma unroll
    for (int k = 0; k < 5; ++k) bx[k] = coef[64 + k];
#pragma unroll
    for (int k = 0; k < 5; ++k) czc[k] = coef[35 + k];
#pragma unroll
    for (int k = 0; k < 9; ++k) cxc[k] = coef[69 + k];
    const int rr = threadIdx.x >> 4;           // 0..15
    const int cc = (threadIdx.x & 15) * 2;     // 0,2,..,30
    float2 R1[9], R2[7], R3[7];
#pragma unroll
    for (int k = 0; k < 9; ++k) R1[k] = make_float2(0.f, 0.f);
#pragma unroll
    for (int k = 0; k < 7; ++k) { R2[k] = make_float2(0.f, 0.f); R3[k] = make_float2(0.f, 0.f); }

    for (int s = z0 - 4; s < z0 + SEG + 4; ++s) {
        const bool inz = (s >= 0 && s < D);
        if (inz) {
            const float* sl = xs + (long long)s * DD;
            for (int li = threadIdx.x; li < 240; li += 256)
                st_task41(raw, li, ld_task10(sl, ty0 - 4, tx0 - 4, li));
        }
        __syncthreads();
        if (inz && threadIdx.x < 192) {
            const int r = threadIdx.x >> 3, g = threadIdx.x & 7;
            const float* rp = &raw[r * 41 + 4 * g];
            float win[12];
#pragma unroll
            for (int i = 0; i < 12; ++i) win[i] = rp[i];
            float4 o1 = make_float4(0.f, 0.f, 0.f, 0.f);
            float4 o2 = make_float4(0.f, 0.f, 0.f, 0.f);
#pragma unroll
            for (int k = 0; k < 5; ++k) {
                o1.x += czc[k] * win[2 + k];
                o1.y += czc[k] * win[3 + k];
                o1.z += czc[k] * win[4 + k];
                o1.w += czc[k] * win[5 + k];
            }
#pragma unroll
            for (int k = 0; k < 9; ++k) {
                o2.x += cxc[k] * win[k];
                o2.y += cxc[k] * win[1 + k];
                o2.z += cxc[k] * win[2 + k];
                o2.w += cxc[k] * win[3 + k];
            }
            *(float4*)&X1[r][4 * g] = o1;
            *(float4*)&X2[r][4 * g] = o2;
        }
        __syncthreads();
        float2 t1 = make_float2(0.f, 0.f), t2 = t1, t3 = t1;
        if (inz) {
#pragma unroll
            for (int k = 0; k < 5; ++k) {
                const float2 v = *(const float2*)&X1[rr + 2 + k][cc];
                t1.x += bz[k] * v.x; t1.y += bz[k] * v.y;
            }
#pragma unroll
            for (int k = 0; k < 9; ++k) {
                const float2 v = *(const float2*)&X1[rr + k][cc];
                t2.x += by[k] * v.x; t2.y += by[k] * v.y;
            }
#pragma unroll
            for (int k = 0; k < 5; ++k) {
                const float2 v = *(const float2*)&X2[rr + 2 + k][cc];
                t3.x += bx[k] * v.x; t3.y += bx[k] * v.y;
            }
        }
#pragma unroll
        for (int k = 0; k < 8; ++k) R1[k] = R1[k + 1];
        R1[8] = t1;
#pragma unroll
        for (int k = 0; k < 6; ++k) { R2[k] = R2[k + 1]; R3[k] = R3[k + 1]; }
        R2[6] = t2; R3[6] = t3;
        const int z = s - 4;
        if (z >= z0) {
            float gz0 = 0.f, gz1 = 0.f, gy0 = 0.f, gy1 = 0.f, gx0 = 0.f, gx1 = 0.f;
#pragma unroll
            for (int k = 0; k < 9; ++k) { gz0 += az[k] * R1[k].x; gz1 += az[k] * R1[k].y; }
#pragma unroll
            for (int k = 0; k < 5; ++k) {
                gy0 += ay[k] * R2[k].x; gy1 += ay[k] * R2[k].y;
                gx0 += ax[k] * R3[k].x; gx1 += ax[k] * R3[k].y;
            }
            float* o = G + (long long)z * DD + (ty0 + rr) * D + tx0 + cc;
            float2 wv;
            wv.x = gz0; wv.y = gz1; *(float2*)(o + 0 * V) = wv;
            wv.x = gy0; wv.y = gy1; *(float2*)(o + 1 * V) = wv;
            wv.x = gx0; wv.y = gx1; *(float2*)(o + 2 * V) = wv;
        }
    }
}

extern "C" void kernel_launch(void* const* d_in, const int* in_sizes, int n_in,
                              void* d_out, int out_size, void* d_ws, size_t ws_size,
                              hipStream_t stream) {
    const float* x  = (const float*)d_in[0];
    const float* g3 = (const float*)d_in[1];
    const float* kz = (const float*)d_in[2];
    const float* ky = (const float*)d_in[3];
    const float* kx = (const float*)d_in[4];
    float* out = (float*)d_out;

    float* coef = (float*)d_ws;
    float* G  = coef + 128;          // 3*V floats (gz, gy, gx)
    float* xs = G + 3 * V;           // V floats

    setup_coef<<<1, 64, 0, stream>>>(g3, kz, ky, kx, coef);

    // S1: Gaussian pre-smooth  x -> xs   (36 tiles x 32 segs = 1152 blocks)
    blur3d<6, 1, false><<<1152, 256, 0, stream>>>(x, xs, coef);

    // S2: gradients  xs -> G[3]         (72 tiles x 12 segs = 864 blocks, z-amp 1.5)
    grad3d<16><<<864, 256, 0, stream>>>(xs, G, coef);

    // S3: products-on-the-fly + grouped smoothing  G -> out
    //     (36 tiles x 6 ch x 6 segs = 1296 blocks, z-amp 1.19)
    blur3d<32, 6, true><<<1296, 256, 0, stream>>>(G, out, coef);
}